// Round 1
// baseline (342.961 us; speedup 1.0000x reference)
//
#include <hip/hip_runtime.h>
#include <math.h>

#define NN 50000
#define EE 800000
#define DDIM 128
#define NROWS 100000   // B*N

__device__ __forceinline__ float lrelu(float x) { return x > 0.f ? x : 0.2f * x; }
__device__ __forceinline__ float eluf(float x)  { return x > 0.f ? x : expm1f(x); }

// ---------------------------------------------------------------------------
// GEMM: Wh[row][o] = sum_k h[row][k] * Wfc[o][k],  rows = B*N = 100000
// block: 256 threads, 32 rows x 128 cols per block, 4x4 register tile
// ---------------------------------------------------------------------------
__global__ __launch_bounds__(256) void gemm_kernel(const float* __restrict__ h,
                                                   const float* __restrict__ Wfc,
                                                   float* __restrict__ Wh) {
    __shared__ float Ws[DDIM * DDIM];   // [k][c]  (transposed W)
    __shared__ float hs[32 * DDIM];     // [r][k]
    const int tid = threadIdx.x;

    // stage W transposed: thread handles column c, strided k quads
    const int c  = tid & 127;
    const int kq = tid >> 7;   // 0..1
#pragma unroll
    for (int rep = 0; rep < 16; ++rep) {
        int k0 = (kq + 2 * rep) << 2;                 // 0,8,..,120 / 4,12,..,124
        float4 w = *(const float4*)&Wfc[c * DDIM + k0];
        Ws[(k0 + 0) * DDIM + c] = w.x;
        Ws[(k0 + 1) * DDIM + c] = w.y;
        Ws[(k0 + 2) * DDIM + c] = w.z;
        Ws[(k0 + 3) * DDIM + c] = w.w;
    }
    // stage 32 rows of h
    const long rowbase = (long)blockIdx.x * 32;
    const float* hblk = h + rowbase * DDIM;
#pragma unroll
    for (int rep = 0; rep < 4; ++rep) {
        int idx = rep * 256 + tid;                    // float4 index 0..1023
        *(float4*)&hs[idx * 4] = *(const float4*)&hblk[idx * 4];
    }
    __syncthreads();

    const int c0 = (tid & 31) * 4;
    const int r0 = (tid >> 5) * 4;
    float4 a0 = {0,0,0,0}, a1 = {0,0,0,0}, a2 = {0,0,0,0}, a3 = {0,0,0,0};
#pragma unroll 4
    for (int k = 0; k < DDIM; ++k) {
        float4 w4 = *(const float4*)&Ws[k * DDIM + c0];
        float h0 = hs[(r0 + 0) * DDIM + k];
        float h1 = hs[(r0 + 1) * DDIM + k];
        float h2 = hs[(r0 + 2) * DDIM + k];
        float h3 = hs[(r0 + 3) * DDIM + k];
        a0.x += h0 * w4.x; a0.y += h0 * w4.y; a0.z += h0 * w4.z; a0.w += h0 * w4.w;
        a1.x += h1 * w4.x; a1.y += h1 * w4.y; a1.z += h1 * w4.z; a1.w += h1 * w4.w;
        a2.x += h2 * w4.x; a2.y += h2 * w4.y; a2.z += h2 * w4.z; a2.w += h2 * w4.w;
        a3.x += h3 * w4.x; a3.y += h3 * w4.y; a3.z += h3 * w4.z; a3.w += h3 * w4.w;
    }
    float* o = Wh + (rowbase + r0) * DDIM + c0;
    *(float4*)&o[0 * DDIM] = a0;
    *(float4*)&o[1 * DDIM] = a1;
    *(float4*)&o[2 * DDIM] = a2;
    *(float4*)&o[3 * DDIM] = a3;
}

// ---------------------------------------------------------------------------
// scores: s_src[row] = Wh[row]·a_src ; s_dst[row] = Wh[row]·a_dst
// one wave per row
// ---------------------------------------------------------------------------
__global__ __launch_bounds__(256) void scores_kernel(const float* __restrict__ Wh,
                                                     const float* __restrict__ Wat,
                                                     float* __restrict__ ssrc,
                                                     float* __restrict__ sdst) {
    const int lane = threadIdx.x & 63;
    const int wid  = threadIdx.x >> 6;
    const long row = (long)blockIdx.x * 4 + wid;
    if (row >= NROWS) return;
    float2 w  = *(const float2*)&Wh[row * DDIM + lane * 2];
    float2 as = *(const float2*)&Wat[lane * 2];
    float2 ad = *(const float2*)&Wat[DDIM + lane * 2];
    float p0 = w.x * as.x + w.y * as.y;
    float p1 = w.x * ad.x + w.y * ad.y;
#pragma unroll
    for (int o = 32; o > 0; o >>= 1) {
        p0 += __shfl_xor(p0, o);
        p1 += __shfl_xor(p1, o);
    }
    if (lane == 0) { ssrc[row] = p0; sdst[row] = p1; }
}

// ---------------------------------------------------------------------------
// CSR build
// ---------------------------------------------------------------------------
__global__ __launch_bounds__(256) void degree_kernel(const int* __restrict__ ei,
                                                     int* __restrict__ deg) {
    int e = blockIdx.x * 256 + threadIdx.x;
    if (e < EE) atomicAdd(&deg[ei[EE + e]], 1);
}

// single block, 1024 threads: exclusive prefix scan of deg into offs
__global__ __launch_bounds__(1024) void scan_kernel(const int* __restrict__ deg,
                                                    int* __restrict__ offs) {
    __shared__ int wsum[16];
    __shared__ int carry_s;
    const int tid = threadIdx.x, lane = tid & 63, wid = tid >> 6;
    if (tid == 0) carry_s = 0;
    __syncthreads();
    for (int base = 0; base < NN; base += 1024) {
        int i = base + tid;
        int v = (i < NN) ? deg[i] : 0;
        int x = v;
#pragma unroll
        for (int o = 1; o < 64; o <<= 1) {
            int t = __shfl_up(x, o);
            if (lane >= o) x += t;
        }
        if (lane == 63) wsum[wid] = x;
        __syncthreads();
        if (wid == 0) {
            int s = (lane < 16) ? wsum[lane] : 0;
#pragma unroll
            for (int o = 1; o < 16; o <<= 1) {
                int t = __shfl_up(s, o);
                if (lane >= o) s += t;
            }
            if (lane < 16) wsum[lane] = s;
        }
        __syncthreads();
        int waveoff = (wid > 0) ? wsum[wid - 1] : 0;
        int incl = x + waveoff;
        int carry = carry_s;
        if (i < NN) offs[i] = carry + incl - v;   // exclusive
        __syncthreads();
        if (tid == 1023) carry_s = carry + incl;
        __syncthreads();
    }
    if (threadIdx.x == 0) offs[NN] = carry_s;     // = EE
}

__global__ __launch_bounds__(256) void scatter_kernel(const int* __restrict__ ei,
                                                      const int* __restrict__ offs,
                                                      int* __restrict__ cnt2,
                                                      int* __restrict__ slist) {
    int e = blockIdx.x * 256 + threadIdx.x;
    if (e < EE) {
        int dst = ei[EE + e];
        int src = ei[e];
        int p = offs[dst] + atomicAdd(&cnt2[dst], 1);
        slist[p] = src;
    }
}

// ---------------------------------------------------------------------------
// aggregate: one wave per destination node; both batches in the wave.
// pass A: segment max, pass B: exp-sum (denom), pass C: weighted message sum.
// ---------------------------------------------------------------------------
__global__ __launch_bounds__(256) void aggregate_kernel(const float* __restrict__ Wh,
                                                        const float* __restrict__ ssrc,
                                                        const float* __restrict__ sdst,
                                                        const int* __restrict__ offs,
                                                        const int* __restrict__ slist,
                                                        float* __restrict__ out) {
    const int lane = threadIdx.x & 63;
    const int wid  = threadIdx.x >> 6;
    const int d    = blockIdx.x * 4 + wid;
    if (d >= NN) return;

    float* out0 = out + (long)d * DDIM;
    float* out1 = out + (long)(NN + d) * DDIM;

    const int base   = offs[d];
    const int degree = offs[d + 1] - base;
    if (degree == 0) {
        float2 z = {0.f, 0.f};
        ((float2*)out0)[lane] = z;
        ((float2*)out1)[lane] = z;
        return;
    }

    const float sd0 = sdst[d];
    const float sd1 = sdst[NN + d];

    // pass A: max
    float m0 = -1e30f, m1 = -1e30f;
    for (int i = lane; i < degree; i += 64) {
        int s = slist[base + i];
        m0 = fmaxf(m0, lrelu(ssrc[s] + sd0));
        m1 = fmaxf(m1, lrelu(ssrc[NN + s] + sd1));
    }
#pragma unroll
    for (int o = 32; o > 0; o >>= 1) {
        m0 = fmaxf(m0, __shfl_xor(m0, o));
        m1 = fmaxf(m1, __shfl_xor(m1, o));
    }

    // pass B: denom
    float sum0 = 0.f, sum1 = 0.f;
    for (int i = lane; i < degree; i += 64) {
        int s = slist[base + i];
        sum0 += __expf(lrelu(ssrc[s] + sd0) - m0);
        sum1 += __expf(lrelu(ssrc[NN + s] + sd1) - m1);
    }
#pragma unroll
    for (int o = 32; o > 0; o >>= 1) {
        sum0 += __shfl_xor(sum0, o);
        sum1 += __shfl_xor(sum1, o);
    }
    const float inv0 = 1.f / sum0;
    const float inv1 = 1.f / sum1;

    // pass C: weighted feature accumulation (64 lanes cover 128 dims as float2)
    float2 acc0 = {0.f, 0.f}, acc1 = {0.f, 0.f};
    for (int ch = 0; ch < degree; ch += 64) {
        int i = ch + lane;
        int s = 0; float w0 = 0.f, w1 = 0.f;
        if (i < degree) {
            s  = slist[base + i];
            w0 = __expf(lrelu(ssrc[s] + sd0) - m0) * inv0;
            w1 = __expf(lrelu(ssrc[NN + s] + sd1) - m1) * inv1;
        }
        int cnt = min(64, degree - ch);
        for (int j = 0; j < cnt; ++j) {
            int   sj  = __shfl(s, j);
            float w0j = __shfl(w0, j);
            float w1j = __shfl(w1, j);
            float2 x0 = *(const float2*)&Wh[(long)sj * DDIM + lane * 2];
            float2 x1 = *(const float2*)&Wh[(long)(NN + sj) * DDIM + lane * 2];
            acc0.x += w0j * x0.x; acc0.y += w0j * x0.y;
            acc1.x += w1j * x1.x; acc1.y += w1j * x1.y;
        }
    }

    float2 r0 = { eluf(acc0.x), eluf(acc0.y) };
    float2 r1 = { eluf(acc1.x), eluf(acc1.y) };
    ((float2*)out0)[lane] = r0;
    ((float2*)out1)[lane] = r1;
}

// ---------------------------------------------------------------------------
extern "C" void kernel_launch(void* const* d_in, const int* in_sizes, int n_in,
                              void* d_out, int out_size, void* d_ws, size_t ws_size,
                              hipStream_t stream) {
    (void)in_sizes; (void)n_in; (void)out_size; (void)ws_size;
    const float* h   = (const float*)d_in[0];
    const int*   ei  = (const int*)d_in[1];
    const float* Wfc = (const float*)d_in[2];
    const float* Wat = (const float*)d_in[3];
    float* out = (float*)d_out;

    char* ws = (char*)d_ws;
    float* Wh   = (float*)(ws + 0);           // 51,200,000 B
    float* ssrc = (float*)(ws + 51200000);    //    400,000 B
    float* sdst = (float*)(ws + 51600000);    //    400,000 B
    int*   slist= (int*)  (ws + 52000000);    //  3,200,000 B
    int*   offs = (int*)  (ws + 55200000);    //    200,448 B (padded)
    int*   deg  = (int*)  (ws + 55400448);    //    200,000 B
    int*   cnt2 = (int*)  (ws + 55600448);    //    200,000 B (contiguous w/ deg)

    hipMemsetAsync(deg, 0, 400000, stream);   // zero deg + cnt2

    gemm_kernel<<<NROWS / 32, 256, 0, stream>>>(h, Wfc, Wh);
    scores_kernel<<<NROWS / 4, 256, 0, stream>>>(Wh, Wat, ssrc, sdst);
    degree_kernel<<<EE / 256, 256, 0, stream>>>(ei, deg);
    scan_kernel<<<1, 1024, 0, stream>>>(deg, offs);
    scatter_kernel<<<EE / 256, 256, 0, stream>>>(ei, offs, cnt2, slist);
    aggregate_kernel<<<NN / 4, 256, 0, stream>>>(Wh, ssrc, sdst, offs, slist, out);
}

// Round 4
// 300.449 us; speedup vs baseline: 1.1415x; 1.1415x over previous
//
#include <hip/hip_runtime.h>
#include <math.h>

#define NN 50000
#define EE 800000
#define DDIM 128
#define NROWS 100000   // B*N

__device__ __forceinline__ float lrelu(float x) { return x > 0.f ? x : 0.2f * x; }
__device__ __forceinline__ float eluf(float x)  { return x > 0.f ? x : expm1f(x); }

__device__ __forceinline__ unsigned short f2bf(float f) {
    unsigned int u = __float_as_uint(f);
    u += 0x7fffu + ((u >> 16) & 1u);          // RNE
    return (unsigned short)(u >> 16);
}
__device__ __forceinline__ float bflo(unsigned int v) { return __uint_as_float(v << 16); }
__device__ __forceinline__ float bfhi(unsigned int v) { return __uint_as_float(v & 0xffff0000u); }

// ---------------------------------------------------------------------------
// GEMM: Wh[row][o] = sum_k h[row][k] * Wfc[o][k]  -> bf16 Wh16
// fused epilogue: ssrc[row] = Wh[row]·a_src, sdst[row] = Wh[row]·a_dst (fp32)
// block: 256 threads, 32 rows x 128 cols, 4x4 register tile
// ---------------------------------------------------------------------------
__global__ __launch_bounds__(256) void gemm_kernel(const float* __restrict__ h,
                                                   const float* __restrict__ Wfc,
                                                   const float* __restrict__ Wat,
                                                   unsigned short* __restrict__ Wh16,
                                                   float* __restrict__ ssrc,
                                                   float* __restrict__ sdst) {
    __shared__ float Ws[DDIM * DDIM];   // [k][c]  (transposed W)
    __shared__ float hs[32 * DDIM];     // [r][k]
    const int tid = threadIdx.x;

    const int c  = tid & 127;
    const int kq = tid >> 7;   // 0..1
#pragma unroll
    for (int rep = 0; rep < 16; ++rep) {
        int k0 = (kq + 2 * rep) << 2;
        float4 w = *(const float4*)&Wfc[c * DDIM + k0];
        Ws[(k0 + 0) * DDIM + c] = w.x;
        Ws[(k0 + 1) * DDIM + c] = w.y;
        Ws[(k0 + 2) * DDIM + c] = w.z;
        Ws[(k0 + 3) * DDIM + c] = w.w;
    }
    const long rowbase = (long)blockIdx.x * 32;
    const float* hblk = h + rowbase * DDIM;
#pragma unroll
    for (int rep = 0; rep < 4; ++rep) {
        int idx = rep * 256 + tid;
        *(float4*)&hs[idx * 4] = *(const float4*)&hblk[idx * 4];
    }
    __syncthreads();

    const int c0 = (tid & 31) * 4;
    const int r0 = (tid >> 5) * 4;
    float4 a0 = {0,0,0,0}, a1 = {0,0,0,0}, a2 = {0,0,0,0}, a3 = {0,0,0,0};
#pragma unroll 4
    for (int k = 0; k < DDIM; ++k) {
        float4 w4 = *(const float4*)&Ws[k * DDIM + c0];
        float h0 = hs[(r0 + 0) * DDIM + k];
        float h1 = hs[(r0 + 1) * DDIM + k];
        float h2 = hs[(r0 + 2) * DDIM + k];
        float h3 = hs[(r0 + 3) * DDIM + k];
        a0.x += h0 * w4.x; a0.y += h0 * w4.y; a0.z += h0 * w4.z; a0.w += h0 * w4.w;
        a1.x += h1 * w4.x; a1.y += h1 * w4.y; a1.z += h1 * w4.z; a1.w += h1 * w4.w;
        a2.x += h2 * w4.x; a2.y += h2 * w4.y; a2.z += h2 * w4.z; a2.w += h2 * w4.w;
        a3.x += h3 * w4.x; a3.y += h3 * w4.y; a3.z += h3 * w4.z; a3.w += h3 * w4.w;
    }

    // ---- bf16 store of the tile ----
    unsigned short* o = Wh16 + (rowbase + r0) * DDIM + c0;
    ushort4 u;
    u.x = f2bf(a0.x); u.y = f2bf(a0.y); u.z = f2bf(a0.z); u.w = f2bf(a0.w);
    *(ushort4*)&o[0 * DDIM] = u;
    u.x = f2bf(a1.x); u.y = f2bf(a1.y); u.z = f2bf(a1.z); u.w = f2bf(a1.w);
    *(ushort4*)&o[1 * DDIM] = u;
    u.x = f2bf(a2.x); u.y = f2bf(a2.y); u.z = f2bf(a2.z); u.w = f2bf(a2.w);
    *(ushort4*)&o[2 * DDIM] = u;
    u.x = f2bf(a3.x); u.y = f2bf(a3.y); u.z = f2bf(a3.z); u.w = f2bf(a3.w);
    *(ushort4*)&o[3 * DDIM] = u;

    // ---- fused scores: reduce tile against a_src / a_dst over 32 lanes ----
    float4 as4 = *(const float4*)&Wat[c0];
    float4 ad4 = *(const float4*)&Wat[DDIM + c0];
    float ps0 = a0.x*as4.x + a0.y*as4.y + a0.z*as4.z + a0.w*as4.w;
    float ps1 = a1.x*as4.x + a1.y*as4.y + a1.z*as4.z + a1.w*as4.w;
    float ps2 = a2.x*as4.x + a2.y*as4.y + a2.z*as4.z + a2.w*as4.w;
    float ps3 = a3.x*as4.x + a3.y*as4.y + a3.z*as4.z + a3.w*as4.w;
    float pd0 = a0.x*ad4.x + a0.y*ad4.y + a0.z*ad4.z + a0.w*ad4.w;
    float pd1 = a1.x*ad4.x + a1.y*ad4.y + a1.z*ad4.z + a1.w*ad4.w;
    float pd2 = a2.x*ad4.x + a2.y*ad4.y + a2.z*ad4.z + a2.w*ad4.w;
    float pd3 = a3.x*ad4.x + a3.y*ad4.y + a3.z*ad4.z + a3.w*ad4.w;
#pragma unroll
    for (int o2 = 1; o2 <= 16; o2 <<= 1) {
        ps0 += __shfl_xor(ps0, o2); ps1 += __shfl_xor(ps1, o2);
        ps2 += __shfl_xor(ps2, o2); ps3 += __shfl_xor(ps3, o2);
        pd0 += __shfl_xor(pd0, o2); pd1 += __shfl_xor(pd1, o2);
        pd2 += __shfl_xor(pd2, o2); pd3 += __shfl_xor(pd3, o2);
    }
    if ((tid & 31) == 0) {
        long r = rowbase + r0;
        ssrc[r + 0] = ps0; ssrc[r + 1] = ps1; ssrc[r + 2] = ps2; ssrc[r + 3] = ps3;
        sdst[r + 0] = pd0; sdst[r + 1] = pd1; sdst[r + 2] = pd2; sdst[r + 3] = pd3;
    }
}

// ---------------------------------------------------------------------------
// CSR build
// ---------------------------------------------------------------------------
__global__ __launch_bounds__(256) void degree_kernel(const int* __restrict__ ei,
                                                     int* __restrict__ deg) {
    int e = blockIdx.x * 256 + threadIdx.x;
    if (e < EE) atomicAdd(&deg[ei[EE + e]], 1);
}

__global__ __launch_bounds__(1024) void scan_kernel(const int* __restrict__ deg,
                                                    int* __restrict__ offs) {
    __shared__ int wsum[16];
    __shared__ int carry_s;
    const int tid = threadIdx.x, lane = tid & 63, wid = tid >> 6;
    if (tid == 0) carry_s = 0;
    __syncthreads();
    for (int base = 0; base < NN; base += 1024) {
        int i = base + tid;
        int v = (i < NN) ? deg[i] : 0;
        int x = v;
#pragma unroll
        for (int o = 1; o < 64; o <<= 1) {
            int t = __shfl_up(x, o);
            if (lane >= o) x += t;
        }
        if (lane == 63) wsum[wid] = x;
        __syncthreads();
        if (wid == 0) {
            int s = (lane < 16) ? wsum[lane] : 0;
#pragma unroll
            for (int o = 1; o < 16; o <<= 1) {
                int t = __shfl_up(s, o);
                if (lane >= o) s += t;
            }
            if (lane < 16) wsum[lane] = s;
        }
        __syncthreads();
        int waveoff = (wid > 0) ? wsum[wid - 1] : 0;
        int incl = x + waveoff;
        int carry = carry_s;
        if (i < NN) offs[i] = carry + incl - v;   // exclusive
        __syncthreads();
        if (tid == 1023) carry_s = carry + incl;
        __syncthreads();
    }
    if (threadIdx.x == 0) offs[NN] = carry_s;     // = EE
}

// scatter + per-edge unnormalized softmax numerator (both batches)
__global__ __launch_bounds__(256) void scatter_kernel(const int* __restrict__ ei,
                                                      const int* __restrict__ offs,
                                                      int* __restrict__ cnt2,
                                                      const float* __restrict__ ssrc,
                                                      const float* __restrict__ sdst,
                                                      int* __restrict__ slist,
                                                      float2* __restrict__ elist) {
    int e = blockIdx.x * 256 + threadIdx.x;
    if (e < EE) {
        int dst = ei[EE + e];
        int src = ei[e];
        int p = offs[dst] + atomicAdd(&cnt2[dst], 1);
        float e0 = __expf(lrelu(ssrc[src]      + sdst[dst]));
        float e1 = __expf(lrelu(ssrc[NN + src] + sdst[NN + dst]));
        slist[p] = src;
        elist[p] = make_float2(e0, e1);
    }
}

// ---------------------------------------------------------------------------
// aggregate: one wave per destination node; both batches; SINGLE pass.
// out = elu( (sum_e w_e * Wh[src_e]) / (sum_e w_e) )
// ---------------------------------------------------------------------------
__global__ __launch_bounds__(256) void aggregate_kernel(const unsigned int* __restrict__ Wh16u,
                                                        const int* __restrict__ offs,
                                                        const int* __restrict__ slist,
                                                        const float2* __restrict__ elist,
                                                        float* __restrict__ out) {
    const int lane = threadIdx.x & 63;
    const int wid  = threadIdx.x >> 6;
    const int d    = blockIdx.x * 4 + wid;
    if (d >= NN) return;

    float* out0 = out + (long)d * DDIM;
    float* out1 = out + (long)(NN + d) * DDIM;

    const int base   = offs[d];
    const int degree = offs[d + 1] - base;
    if (degree == 0) {
        float2 z = {0.f, 0.f};
        ((float2*)out0)[lane] = z;
        ((float2*)out1)[lane] = z;
        return;
    }

    float2 acc0 = {0.f, 0.f}, acc1 = {0.f, 0.f};
    float ds0 = 0.f, ds1 = 0.f;

    for (int ch = 0; ch < degree; ch += 64) {
        int i = ch + lane;
        int s = 0; float w0 = 0.f, w1 = 0.f;
        if (i < degree) {
            s = slist[base + i];
            float2 ev = elist[base + i];
            w0 = ev.x; w1 = ev.y;
            ds0 += w0; ds1 += w1;
        }
        int cnt = min(64, degree - ch);
        for (int j = 0; j < cnt; ++j) {
            int   sj  = __shfl(s, j);
            float w0j = __shfl(w0, j);
            float w1j = __shfl(w1, j);
            unsigned int v0 = Wh16u[(long)sj * 64 + lane];
            unsigned int v1 = Wh16u[(long)(NN + sj) * 64 + lane];
            acc0.x += w0j * bflo(v0); acc0.y += w0j * bfhi(v0);
            acc1.x += w1j * bflo(v1); acc1.y += w1j * bfhi(v1);
        }
    }

#pragma unroll
    for (int o = 32; o > 0; o >>= 1) {
        ds0 += __shfl_xor(ds0, o);
        ds1 += __shfl_xor(ds1, o);
    }
    const float inv0 = 1.f / ds0;
    const float inv1 = 1.f / ds1;

    float2 r0 = { eluf(acc0.x * inv0), eluf(acc0.y * inv0) };
    float2 r1 = { eluf(acc1.x * inv1), eluf(acc1.y * inv1) };
    ((float2*)out0)[lane] = r0;
    ((float2*)out1)[lane] = r1;
}

// ---------------------------------------------------------------------------
extern "C" void kernel_launch(void* const* d_in, const int* in_sizes, int n_in,
                              void* d_out, int out_size, void* d_ws, size_t ws_size,
                              hipStream_t stream) {
    (void)in_sizes; (void)n_in; (void)out_size; (void)ws_size;
    const float* h   = (const float*)d_in[0];
    const int*   ei  = (const int*)d_in[1];
    const float* Wfc = (const float*)d_in[2];
    const float* Wat = (const float*)d_in[3];
    float* out = (float*)d_out;

    char* ws = (char*)d_ws;
    unsigned short* Wh16 = (unsigned short*)(ws + 0);   // 25,600,000 B
    float*  ssrc = (float*) (ws + 25600000);            //    400,000 B
    float*  sdst = (float*) (ws + 26000000);            //    400,000 B
    int*    slist= (int*)   (ws + 26400000);            //  3,200,000 B
    float2* elist= (float2*)(ws + 29600000);            //  6,400,000 B
    int*    offs = (int*)   (ws + 36000000);            //    200,448 B
    int*    deg  = (int*)   (ws + 36200448);            //    200,000 B
    int*    cnt2 = (int*)   (ws + 36400448);            //    200,000 B (contiguous w/ deg)

    hipMemsetAsync(deg, 0, 400000, stream);   // zero deg + cnt2

    gemm_kernel<<<NROWS / 32, 256, 0, stream>>>(h, Wfc, Wat, Wh16, ssrc, sdst);
    degree_kernel<<<EE / 256, 256, 0, stream>>>(ei, deg);
    scan_kernel<<<1, 1024, 0, stream>>>(deg, offs);
    scatter_kernel<<<EE / 256, 256, 0, stream>>>(ei, offs, cnt2, ssrc, sdst, slist, elist);
    aggregate_kernel<<<NN / 4, 256, 0, stream>>>((const unsigned int*)Wh16, offs, slist, elist, out);
}

// Round 5
// 233.223 us; speedup vs baseline: 1.4705x; 1.2882x over previous
//
#include <hip/hip_runtime.h>
#include <math.h>

#define NN 50000
#define EE 800000
#define DDIM 128
#define NROWS 100000   // B*N
#define NB 49          // ceil(NN/1024) scan blocks

__device__ __forceinline__ float lrelu(float x) { return x > 0.f ? x : 0.2f * x; }
__device__ __forceinline__ float eluf(float x)  { return x > 0.f ? x : expm1f(x); }

__device__ __forceinline__ unsigned short f2bf(float f) {
    unsigned int u = __float_as_uint(f);
    u += 0x7fffu + ((u >> 16) & 1u);          // RNE
    return (unsigned short)(u >> 16);
}
__device__ __forceinline__ float bflo(unsigned int v) { return __uint_as_float(v << 16); }
__device__ __forceinline__ float bfhi(unsigned int v) { return __uint_as_float(v & 0xffff0000u); }

// ---------------------------------------------------------------------------
// GEMM: Wh[row][o] = sum_k h[row][k] * Wfc[o][k]  -> bf16 Wh16
// fused epilogue: ssrc/sdst scores (fp32)
// ---------------------------------------------------------------------------
__global__ __launch_bounds__(256) void gemm_kernel(const float* __restrict__ h,
                                                   const float* __restrict__ Wfc,
                                                   const float* __restrict__ Wat,
                                                   unsigned short* __restrict__ Wh16,
                                                   float* __restrict__ ssrc,
                                                   float* __restrict__ sdst) {
    __shared__ float Ws[DDIM * DDIM];   // [k][c]  (transposed W)
    __shared__ float hs[32 * DDIM];     // [r][k]
    const int tid = threadIdx.x;

    const int c  = tid & 127;
    const int kq = tid >> 7;   // 0..1
#pragma unroll
    for (int rep = 0; rep < 16; ++rep) {
        int k0 = (kq + 2 * rep) << 2;
        float4 w = *(const float4*)&Wfc[c * DDIM + k0];
        Ws[(k0 + 0) * DDIM + c] = w.x;
        Ws[(k0 + 1) * DDIM + c] = w.y;
        Ws[(k0 + 2) * DDIM + c] = w.z;
        Ws[(k0 + 3) * DDIM + c] = w.w;
    }
    const long rowbase = (long)blockIdx.x * 32;
    const float* hblk = h + rowbase * DDIM;
#pragma unroll
    for (int rep = 0; rep < 4; ++rep) {
        int idx = rep * 256 + tid;
        *(float4*)&hs[idx * 4] = *(const float4*)&hblk[idx * 4];
    }
    __syncthreads();

    const int c0 = (tid & 31) * 4;
    const int r0 = (tid >> 5) * 4;
    float4 a0 = {0,0,0,0}, a1 = {0,0,0,0}, a2 = {0,0,0,0}, a3 = {0,0,0,0};
#pragma unroll 4
    for (int k = 0; k < DDIM; ++k) {
        float4 w4 = *(const float4*)&Ws[k * DDIM + c0];
        float h0 = hs[(r0 + 0) * DDIM + k];
        float h1 = hs[(r0 + 1) * DDIM + k];
        float h2 = hs[(r0 + 2) * DDIM + k];
        float h3 = hs[(r0 + 3) * DDIM + k];
        a0.x += h0 * w4.x; a0.y += h0 * w4.y; a0.z += h0 * w4.z; a0.w += h0 * w4.w;
        a1.x += h1 * w4.x; a1.y += h1 * w4.y; a1.z += h1 * w4.z; a1.w += h1 * w4.w;
        a2.x += h2 * w4.x; a2.y += h2 * w4.y; a2.z += h2 * w4.z; a2.w += h2 * w4.w;
        a3.x += h3 * w4.x; a3.y += h3 * w4.y; a3.z += h3 * w4.z; a3.w += h3 * w4.w;
    }

    unsigned short* o = Wh16 + (rowbase + r0) * DDIM + c0;
    ushort4 u;
    u.x = f2bf(a0.x); u.y = f2bf(a0.y); u.z = f2bf(a0.z); u.w = f2bf(a0.w);
    *(ushort4*)&o[0 * DDIM] = u;
    u.x = f2bf(a1.x); u.y = f2bf(a1.y); u.z = f2bf(a1.z); u.w = f2bf(a1.w);
    *(ushort4*)&o[1 * DDIM] = u;
    u.x = f2bf(a2.x); u.y = f2bf(a2.y); u.z = f2bf(a2.z); u.w = f2bf(a2.w);
    *(ushort4*)&o[2 * DDIM] = u;
    u.x = f2bf(a3.x); u.y = f2bf(a3.y); u.z = f2bf(a3.z); u.w = f2bf(a3.w);
    *(ushort4*)&o[3 * DDIM] = u;

    float4 as4 = *(const float4*)&Wat[c0];
    float4 ad4 = *(const float4*)&Wat[DDIM + c0];
    float ps0 = a0.x*as4.x + a0.y*as4.y + a0.z*as4.z + a0.w*as4.w;
    float ps1 = a1.x*as4.x + a1.y*as4.y + a1.z*as4.z + a1.w*as4.w;
    float ps2 = a2.x*as4.x + a2.y*as4.y + a2.z*as4.z + a2.w*as4.w;
    float ps3 = a3.x*as4.x + a3.y*as4.y + a3.z*as4.z + a3.w*as4.w;
    float pd0 = a0.x*ad4.x + a0.y*ad4.y + a0.z*ad4.z + a0.w*ad4.w;
    float pd1 = a1.x*ad4.x + a1.y*ad4.y + a1.z*ad4.z + a1.w*ad4.w;
    float pd2 = a2.x*ad4.x + a2.y*ad4.y + a2.z*ad4.z + a2.w*ad4.w;
    float pd3 = a3.x*ad4.x + a3.y*ad4.y + a3.z*ad4.z + a3.w*ad4.w;
#pragma unroll
    for (int o2 = 1; o2 <= 16; o2 <<= 1) {
        ps0 += __shfl_xor(ps0, o2); ps1 += __shfl_xor(ps1, o2);
        ps2 += __shfl_xor(ps2, o2); ps3 += __shfl_xor(ps3, o2);
        pd0 += __shfl_xor(pd0, o2); pd1 += __shfl_xor(pd1, o2);
        pd2 += __shfl_xor(pd2, o2); pd3 += __shfl_xor(pd3, o2);
    }
    if ((tid & 31) == 0) {
        long r = rowbase + r0;
        ssrc[r + 0] = ps0; ssrc[r + 1] = ps1; ssrc[r + 2] = ps2; ssrc[r + 3] = ps3;
        sdst[r + 0] = pd0; sdst[r + 1] = pd1; sdst[r + 2] = pd2; sdst[r + 3] = pd3;
    }
}

// ---------------------------------------------------------------------------
// CSR build: degree -> 3-kernel parallel exclusive scan -> scatter
// ---------------------------------------------------------------------------
__global__ __launch_bounds__(256) void degree_kernel(const int* __restrict__ ei,
                                                     int* __restrict__ deg) {
    int e = blockIdx.x * 256 + threadIdx.x;
    if (e < EE) atomicAdd(&deg[ei[EE + e]], 1);
}

// per-block exclusive scan of 1024 elements; block sum to bsum
__global__ __launch_bounds__(1024) void scan1_kernel(const int* __restrict__ deg,
                                                     int* __restrict__ offs,
                                                     int* __restrict__ bsum) {
    __shared__ int wsum[16];
    const int tid = threadIdx.x, lane = tid & 63, wid = tid >> 6;
    const int i = blockIdx.x * 1024 + tid;
    int v = (i < NN) ? deg[i] : 0;
    int x = v;
#pragma unroll
    for (int o = 1; o < 64; o <<= 1) {
        int t = __shfl_up(x, o);
        if (lane >= o) x += t;
    }
    if (lane == 63) wsum[wid] = x;
    __syncthreads();
    if (wid == 0) {
        int s = (lane < 16) ? wsum[lane] : 0;
#pragma unroll
        for (int o = 1; o < 16; o <<= 1) {
            int t = __shfl_up(s, o);
            if (lane >= o) s += t;
        }
        if (lane < 16) wsum[lane] = s;
    }
    __syncthreads();
    int waveoff = (wid > 0) ? wsum[wid - 1] : 0;
    if (i < NN) offs[i] = x - v + waveoff;          // block-local exclusive
    if (tid == 0) bsum[blockIdx.x] = wsum[15];      // block total
}

// single wave scans NB block sums; writes exclusive bscan and offs[NN]
__global__ __launch_bounds__(64) void scan2_kernel(const int* __restrict__ bsum,
                                                   int* __restrict__ bscan,
                                                   int* __restrict__ offs) {
    const int lane = threadIdx.x;
    int v = (lane < NB) ? bsum[lane] : 0;
    int x = v;
#pragma unroll
    for (int o = 1; o < 64; o <<= 1) {
        int t = __shfl_up(x, o);
        if (lane >= o) x += t;
    }
    if (lane < NB) bscan[lane] = x - v;
    if (lane == 63) offs[NN] = x;                   // total = EE
}

__global__ __launch_bounds__(1024) void scan3_kernel(int* __restrict__ offs,
                                                     const int* __restrict__ bscan) {
    const int i = blockIdx.x * 1024 + threadIdx.x;
    if (i < NN) offs[i] += bscan[blockIdx.x];
}

// scatter + per-edge unnormalized softmax numerator (both batches)
__global__ __launch_bounds__(256) void scatter_kernel(const int* __restrict__ ei,
                                                      const int* __restrict__ offs,
                                                      int* __restrict__ cnt2,
                                                      const float* __restrict__ ssrc,
                                                      const float* __restrict__ sdst,
                                                      int* __restrict__ slist,
                                                      float2* __restrict__ elist) {
    int e = blockIdx.x * 256 + threadIdx.x;
    if (e < EE) {
        int dst = ei[EE + e];
        int src = ei[e];
        int p = offs[dst] + atomicAdd(&cnt2[dst], 1);
        float e0 = __expf(lrelu(ssrc[src]      + sdst[dst]));
        float e1 = __expf(lrelu(ssrc[NN + src] + sdst[NN + dst]));
        slist[p] = src;
        elist[p] = make_float2(e0, e1);
    }
}

// ---------------------------------------------------------------------------
// aggregate: one wave per dst; lanes 0-31 handle even edges, 32-63 odd edges.
// Each lane owns 4 features (uint2 = 4 bf16) per batch; shfl_xor(32) merge.
// ---------------------------------------------------------------------------
__global__ __launch_bounds__(256) void aggregate_kernel(const unsigned int* __restrict__ Wh16u,
                                                        const int* __restrict__ offs,
                                                        const int* __restrict__ slist,
                                                        const float2* __restrict__ elist,
                                                        float* __restrict__ out) {
    const int lane = threadIdx.x & 63;
    const int wid  = threadIdx.x >> 6;
    const int d    = blockIdx.x * 4 + wid;
    if (d >= NN) return;

    const int hl     = lane & 31;
    const int hiHalf = lane >> 5;   // 0 or 1

    float* out0 = out + (long)d * DDIM;
    float* out1 = out + (long)(NN + d) * DDIM;

    const int base   = offs[d];
    const int degree = offs[d + 1] - base;
    if (degree == 0) {
        float4 z = {0.f, 0.f, 0.f, 0.f};
        if (!hiHalf) ((float4*)out0)[hl] = z;
        else         ((float4*)out1)[hl] = z;
        return;
    }

    float4 acc0 = {0,0,0,0}, acc1 = {0,0,0,0};
    float ds0 = 0.f, ds1 = 0.f;

    for (int ch = 0; ch < degree; ch += 64) {
        int i = ch + lane;
        int s = 0; float w0 = 0.f, w1 = 0.f;
        if (i < degree) {
            s = slist[base + i];
            float2 ev = elist[base + i];
            w0 = ev.x; w1 = ev.y;
            ds0 += w0; ds1 += w1;
        }
        int cnt  = min(64, degree - ch);
        int half = (cnt + 1) >> 1;
        for (int j = 0; j < half; ++j) {
            int idx = 2 * j + hiHalf;            // odd tail: idx==cnt hits a w=0 lane
            int   sj  = __shfl(s,  idx);
            float w0j = __shfl(w0, idx);
            float w1j = __shfl(w1, idx);
            uint2 v0 = ((const uint2*)(Wh16u + (long)sj * 64))[hl];
            uint2 v1 = ((const uint2*)(Wh16u + (long)(NN + sj) * 64))[hl];
            acc0.x += w0j * bflo(v0.x); acc0.y += w0j * bfhi(v0.x);
            acc0.z += w0j * bflo(v0.y); acc0.w += w0j * bfhi(v0.y);
            acc1.x += w1j * bflo(v1.x); acc1.y += w1j * bfhi(v1.x);
            acc1.z += w1j * bflo(v1.y); acc1.w += w1j * bfhi(v1.y);
        }
    }

    // merge even/odd halves (feature sets identical across halves)
    acc0.x += __shfl_xor(acc0.x, 32); acc0.y += __shfl_xor(acc0.y, 32);
    acc0.z += __shfl_xor(acc0.z, 32); acc0.w += __shfl_xor(acc0.w, 32);
    acc1.x += __shfl_xor(acc1.x, 32); acc1.y += __shfl_xor(acc1.y, 32);
    acc1.z += __shfl_xor(acc1.z, 32); acc1.w += __shfl_xor(acc1.w, 32);

#pragma unroll
    for (int o = 32; o > 0; o >>= 1) {
        ds0 += __shfl_xor(ds0, o);
        ds1 += __shfl_xor(ds1, o);
    }
    const float inv0 = 1.f / ds0;
    const float inv1 = 1.f / ds1;

    if (!hiHalf) {
        float4 r = { eluf(acc0.x * inv0), eluf(acc0.y * inv0),
                     eluf(acc0.z * inv0), eluf(acc0.w * inv0) };
        ((float4*)out0)[hl] = r;
    } else {
        float4 r = { eluf(acc1.x * inv1), eluf(acc1.y * inv1),
                     eluf(acc1.z * inv1), eluf(acc1.w * inv1) };
        ((float4*)out1)[hl] = r;
    }
}

// ---------------------------------------------------------------------------
extern "C" void kernel_launch(void* const* d_in, const int* in_sizes, int n_in,
                              void* d_out, int out_size, void* d_ws, size_t ws_size,
                              hipStream_t stream) {
    (void)in_sizes; (void)n_in; (void)out_size; (void)ws_size;
    const float* h   = (const float*)d_in[0];
    const int*   ei  = (const int*)d_in[1];
    const float* Wfc = (const float*)d_in[2];
    const float* Wat = (const float*)d_in[3];
    float* out = (float*)d_out;

    char* ws = (char*)d_ws;
    unsigned short* Wh16 = (unsigned short*)(ws + 0);   // 25,600,000 B
    float*  ssrc = (float*) (ws + 25600000);            //    400,000 B
    float*  sdst = (float*) (ws + 26000000);            //    400,000 B
    int*    slist= (int*)   (ws + 26400000);            //  3,200,000 B
    float2* elist= (float2*)(ws + 29600000);            //  6,400,000 B
    int*    offs = (int*)   (ws + 36000000);            //    200,448 B
    int*    deg  = (int*)   (ws + 36200448);            //    200,000 B
    int*    cnt2 = (int*)   (ws + 36400448);            //    200,000 B (contiguous w/ deg)
    int*    bsum = (int*)   (ws + 36600448);            //        256 B
    int*    bscan= (int*)   (ws + 36600704);            //        256 B

    hipMemsetAsync(deg, 0, 400000, stream);   // zero deg + cnt2

    gemm_kernel<<<NROWS / 32, 256, 0, stream>>>(h, Wfc, Wat, Wh16, ssrc, sdst);
    degree_kernel<<<EE / 256, 256, 0, stream>>>(ei, deg);
    scan1_kernel<<<NB, 1024, 0, stream>>>(deg, offs, bsum);
    scan2_kernel<<<1, 64, 0, stream>>>(bsum, bscan, offs);
    scan3_kernel<<<NB, 1024, 0, stream>>>(offs, bscan);
    scatter_kernel<<<EE / 256, 256, 0, stream>>>(ei, offs, cnt2, ssrc, sdst, slist, elist);
    aggregate_kernel<<<NN / 4, 256, 0, stream>>>((const unsigned int*)Wh16, offs, slist, elist, out);
}

// Round 6
// 190.725 us; speedup vs baseline: 1.7982x; 1.2228x over previous
//
#include <hip/hip_runtime.h>
#include <math.h>

#define NN 50000
#define EE 800000
#define DDIM 128
#define NROWS 100000   // B*N
#define NB 49          // ceil(NN/1024) scan blocks

typedef __attribute__((ext_vector_type(8))) short bf16x8;
typedef __attribute__((ext_vector_type(4))) float f32x4;

__device__ __forceinline__ float lrelu(float x) { return x > 0.f ? x : 0.2f * x; }
__device__ __forceinline__ float eluf(float x)  { return x > 0.f ? x : expm1f(x); }

__device__ __forceinline__ unsigned short f2bf(float f) {
    unsigned int u = __float_as_uint(f);
    u += 0x7fffu + ((u >> 16) & 1u);          // RNE
    return (unsigned short)(u >> 16);
}
__device__ __forceinline__ float bflo(unsigned int v) { return __uint_as_float(v << 16); }
__device__ __forceinline__ float bfhi(unsigned int v) { return __uint_as_float(v & 0xffff0000u); }

// ---------------------------------------------------------------------------
// MFMA GEMM: Wh16[row][o] = bf16( sum_k h[row][k] * Wfc[o][k] )
// + fused scores ssrc/sdst from the fp32 accumulators.
// Block: 256 thr = 4 waves; 64 rows x 128 cols; K=128.
// W staged to LDS bf16 [col][k] with ((col&15)<<4) XOR swizzle.
// MFMA 16x16x32 bf16: A lane layout row=lane&15, k=(lane>>4)*8+e;
//                     B lane layout col=lane&15, k=(lane>>4)*8+e;
//                     D lane layout col=lane&15, row=(lane>>4)*4+reg.
// ---------------------------------------------------------------------------
__global__ __launch_bounds__(256) void gemm_kernel(const float* __restrict__ h,
                                                   const float* __restrict__ Wfc,
                                                   const float* __restrict__ Wat,
                                                   unsigned short* __restrict__ Wh16,
                                                   float* __restrict__ ssrc,
                                                   float* __restrict__ sdst) {
    __shared__ uint4 Wlds4[2048];              // 32 KB: 128 cols x 256 B
    char* WldsB = (char*)Wlds4;
    const int tid = threadIdx.x;

    // ---- stage W -> LDS bf16, swizzled ----
    {
        const int colw = tid & 127;
        const int kh   = tid >> 7;             // 0..1
#pragma unroll
        for (int q = 0; q < 8; ++q) {
            int k0 = kh * 64 + q * 8;
            float4 w0 = *(const float4*)&Wfc[colw * DDIM + k0];
            float4 w1 = *(const float4*)&Wfc[colw * DDIM + k0 + 4];
            union { uint4 q4; unsigned short u[8]; } pk;
            pk.u[0] = f2bf(w0.x); pk.u[1] = f2bf(w0.y);
            pk.u[2] = f2bf(w0.z); pk.u[3] = f2bf(w0.w);
            pk.u[4] = f2bf(w1.x); pk.u[5] = f2bf(w1.y);
            pk.u[6] = f2bf(w1.z); pk.u[7] = f2bf(w1.w);
            int ba = colw * 256 + k0 * 2;
            ba ^= (colw & 15) << 4;
            *(uint4*)(WldsB + ba) = pk.q4;
        }
    }
    __syncthreads();

    const int lane = tid & 63;
    const int wv   = tid >> 6;
    const long mbase = (long)blockIdx.x * 64 + wv * 16;
    if (mbase >= NROWS) return;                // tail block: waves 2,3 idle

    const int c  = lane & 15;                  // A row / D col within tile
    const int kg = lane >> 4;                  // k-group 0..3

    // ---- A fragments: global fp32 -> bf16 regs ----
    union Af { bf16x8 v; unsigned short u[8]; };
    Af af[4];
    const float* arow = h + (mbase + c) * DDIM + kg * 8;
#pragma unroll
    for (int kk = 0; kk < 4; ++kk) {
        float4 x = *(const float4*)(arow + kk * 32);
        float4 y = *(const float4*)(arow + kk * 32 + 4);
        af[kk].u[0] = f2bf(x.x); af[kk].u[1] = f2bf(x.y);
        af[kk].u[2] = f2bf(x.z); af[kk].u[3] = f2bf(x.w);
        af[kk].u[4] = f2bf(y.x); af[kk].u[5] = f2bf(y.y);
        af[kk].u[6] = f2bf(y.z); af[kk].u[7] = f2bf(y.w);
    }

    // ---- MFMA main: 8 col-tiles x 4 k-steps ----
    f32x4 acc[8];
#pragma unroll
    for (int t = 0; t < 8; ++t) acc[t] = (f32x4){0.f, 0.f, 0.f, 0.f};
#pragma unroll
    for (int t = 0; t < 8; ++t) {
        int colbase = (t * 16 + c) * 256;
        int sw = c << 4;
#pragma unroll
        for (int kk = 0; kk < 4; ++kk) {
            int ba = (colbase + kk * 64 + kg * 16) ^ sw;
            bf16x8 b = *(const bf16x8*)(WldsB + ba);
            acc[t] = __builtin_amdgcn_mfma_f32_16x16x32_bf16(af[kk].v, b, acc[t], 0, 0, 0);
        }
    }

    // ---- store Wh16 (D: col = t*16+c, row = mbase + kg*4 + r) ----
#pragma unroll
    for (int t = 0; t < 8; ++t) {
#pragma unroll
        for (int r = 0; r < 4; ++r) {
            Wh16[(mbase + kg * 4 + r) * DDIM + t * 16 + c] = f2bf(acc[t][r]);
        }
    }

    // ---- fused scores ----
    float asv[8], adv[8];
#pragma unroll
    for (int t = 0; t < 8; ++t) {
        asv[t] = Wat[t * 16 + c];
        adv[t] = Wat[DDIM + t * 16 + c];
    }
#pragma unroll
    for (int r = 0; r < 4; ++r) {
        float ps = 0.f, pd = 0.f;
#pragma unroll
        for (int t = 0; t < 8; ++t) {
            ps += acc[t][r] * asv[t];
            pd += acc[t][r] * adv[t];
        }
#pragma unroll
        for (int o = 1; o <= 8; o <<= 1) {
            ps += __shfl_xor(ps, o);
            pd += __shfl_xor(pd, o);
        }
        if (c == 0) {
            long row = mbase + kg * 4 + r;
            ssrc[row] = ps;
            sdst[row] = pd;
        }
    }
}

// ---------------------------------------------------------------------------
// CSR build: degree -> 3-kernel parallel exclusive scan -> scatter
// ---------------------------------------------------------------------------
__global__ __launch_bounds__(256) void degree_kernel(const int* __restrict__ ei,
                                                     int* __restrict__ deg) {
    int e = blockIdx.x * 256 + threadIdx.x;
    if (e < EE) atomicAdd(&deg[ei[EE + e]], 1);
}

__global__ __launch_bounds__(1024) void scan1_kernel(const int* __restrict__ deg,
                                                     int* __restrict__ offs,
                                                     int* __restrict__ bsum) {
    __shared__ int wsum[16];
    const int tid = threadIdx.x, lane = tid & 63, wid = tid >> 6;
    const int i = blockIdx.x * 1024 + tid;
    int v = (i < NN) ? deg[i] : 0;
    int x = v;
#pragma unroll
    for (int o = 1; o < 64; o <<= 1) {
        int t = __shfl_up(x, o);
        if (lane >= o) x += t;
    }
    if (lane == 63) wsum[wid] = x;
    __syncthreads();
    if (wid == 0) {
        int s = (lane < 16) ? wsum[lane] : 0;
#pragma unroll
        for (int o = 1; o < 16; o <<= 1) {
            int t = __shfl_up(s, o);
            if (lane >= o) s += t;
        }
        if (lane < 16) wsum[lane] = s;
    }
    __syncthreads();
    int waveoff = (wid > 0) ? wsum[wid - 1] : 0;
    if (i < NN) offs[i] = x - v + waveoff;          // block-local exclusive
    if (tid == 0) bsum[blockIdx.x] = wsum[15];      // block total
}

__global__ __launch_bounds__(64) void scan2_kernel(const int* __restrict__ bsum,
                                                   int* __restrict__ bscan,
                                                   int* __restrict__ offs) {
    const int lane = threadIdx.x;
    int v = (lane < NB) ? bsum[lane] : 0;
    int x = v;
#pragma unroll
    for (int o = 1; o < 64; o <<= 1) {
        int t = __shfl_up(x, o);
        if (lane >= o) x += t;
    }
    if (lane < NB) bscan[lane] = x - v;
    if (lane == 63) offs[NN] = x;                   // total = EE
}

__global__ __launch_bounds__(1024) void scan3_kernel(int* __restrict__ offs,
                                                     const int* __restrict__ bscan) {
    const int i = blockIdx.x * 1024 + threadIdx.x;
    if (i < NN) offs[i] += bscan[blockIdx.x];
}

// scatter + per-edge unnormalized softmax numerator (both batches)
__global__ __launch_bounds__(256) void scatter_kernel(const int* __restrict__ ei,
                                                      const int* __restrict__ offs,
                                                      int* __restrict__ cnt2,
                                                      const float* __restrict__ ssrc,
                                                      const float* __restrict__ sdst,
                                                      int* __restrict__ slist,
                                                      float2* __restrict__ elist) {
    int e = blockIdx.x * 256 + threadIdx.x;
    if (e < EE) {
        int dst = ei[EE + e];
        int src = ei[e];
        int p = offs[dst] + atomicAdd(&cnt2[dst], 1);
        float e0 = __expf(lrelu(ssrc[src]      + sdst[dst]));
        float e1 = __expf(lrelu(ssrc[NN + src] + sdst[NN + dst]));
        slist[p] = src;
        elist[p] = make_float2(e0, e1);
    }
}

// ---------------------------------------------------------------------------
// aggregate: one wave per dst; lanes 0-31 handle even edges, 32-63 odd edges.
// ---------------------------------------------------------------------------
__global__ __launch_bounds__(256) void aggregate_kernel(const unsigned int* __restrict__ Wh16u,
                                                        const int* __restrict__ offs,
                                                        const int* __restrict__ slist,
                                                        const float2* __restrict__ elist,
                                                        float* __restrict__ out) {
    const int lane = threadIdx.x & 63;
    const int wid  = threadIdx.x >> 6;
    const int d    = blockIdx.x * 4 + wid;
    if (d >= NN) return;

    const int hl     = lane & 31;
    const int hiHalf = lane >> 5;   // 0 or 1

    float* out0 = out + (long)d * DDIM;
    float* out1 = out + (long)(NN + d) * DDIM;

    const int base   = offs[d];
    const int degree = offs[d + 1] - base;
    if (degree == 0) {
        float4 z = {0.f, 0.f, 0.f, 0.f};
        if (!hiHalf) ((float4*)out0)[hl] = z;
        else         ((float4*)out1)[hl] = z;
        return;
    }

    float4 acc0 = {0,0,0,0}, acc1 = {0,0,0,0};
    float ds0 = 0.f, ds1 = 0.f;

    for (int ch = 0; ch < degree; ch += 64) {
        int i = ch + lane;
        int s = 0; float w0 = 0.f, w1 = 0.f;
        if (i < degree) {
            s = slist[base + i];
            float2 ev = elist[base + i];
            w0 = ev.x; w1 = ev.y;
            ds0 += w0; ds1 += w1;
        }
        int cnt  = min(64, degree - ch);
        int half = (cnt + 1) >> 1;
        for (int j = 0; j < half; ++j) {
            int idx = 2 * j + hiHalf;            // odd tail: idx==cnt hits a w=0 lane
            int   sj  = __shfl(s,  idx);
            float w0j = __shfl(w0, idx);
            float w1j = __shfl(w1, idx);
            uint2 v0 = ((const uint2*)(Wh16u + (long)sj * 64))[hl];
            uint2 v1 = ((const uint2*)(Wh16u + (long)(NN + sj) * 64))[hl];
            acc0.x += w0j * bflo(v0.x); acc0.y += w0j * bfhi(v0.x);
            acc0.z += w0j * bflo(v0.y); acc0.w += w0j * bfhi(v0.y);
            acc1.x += w1j * bflo(v1.x); acc1.y += w1j * bfhi(v1.x);
            acc1.z += w1j * bflo(v1.y); acc1.w += w1j * bfhi(v1.y);
        }
    }

    acc0.x += __shfl_xor(acc0.x, 32); acc0.y += __shfl_xor(acc0.y, 32);
    acc0.z += __shfl_xor(acc0.z, 32); acc0.w += __shfl_xor(acc0.w, 32);
    acc1.x += __shfl_xor(acc1.x, 32); acc1.y += __shfl_xor(acc1.y, 32);
    acc1.z += __shfl_xor(acc1.z, 32); acc1.w += __shfl_xor(acc1.w, 32);

#pragma unroll
    for (int o = 32; o > 0; o >>= 1) {
        ds0 += __shfl_xor(ds0, o);
        ds1 += __shfl_xor(ds1, o);
    }
    const float inv0 = 1.f / ds0;
    const float inv1 = 1.f / ds1;

    if (!hiHalf) {
        float4 r = { eluf(acc0.x * inv0), eluf(acc0.y * inv0),
                     eluf(acc0.z * inv0), eluf(acc0.w * inv0) };
        ((float4*)out0)[hl] = r;
    } else {
        float4 r = { eluf(acc1.x * inv1), eluf(acc1.y * inv1),
                     eluf(acc1.z * inv1), eluf(acc1.w * inv1) };
        ((float4*)out1)[hl] = r;
    }
}

// ---------------------------------------------------------------------------
extern "C" void kernel_launch(void* const* d_in, const int* in_sizes, int n_in,
                              void* d_out, int out_size, void* d_ws, size_t ws_size,
                              hipStream_t stream) {
    (void)in_sizes; (void)n_in; (void)out_size; (void)ws_size;
    const float* h   = (const float*)d_in[0];
    const int*   ei  = (const int*)d_in[1];
    const float* Wfc = (const float*)d_in[2];
    const float* Wat = (const float*)d_in[3];
    float* out = (float*)d_out;

    char* ws = (char*)d_ws;
    unsigned short* Wh16 = (unsigned short*)(ws + 0);   // 25,600,000 B
    float*  ssrc = (float*) (ws + 25600000);            //    400,000 B
    float*  sdst = (float*) (ws + 26000000);            //    400,000 B
    int*    slist= (int*)   (ws + 26400000);            //  3,200,000 B
    float2* elist= (float2*)(ws + 29600000);            //  6,400,000 B
    int*    offs = (int*)   (ws + 36000000);            //    200,448 B
    int*    deg  = (int*)   (ws + 36200448);            //    200,000 B
    int*    cnt2 = (int*)   (ws + 36400448);            //    200,000 B (contiguous w/ deg)
    int*    bsum = (int*)   (ws + 36600448);            //        256 B
    int*    bscan= (int*)   (ws + 36600704);            //        256 B

    hipMemsetAsync(deg, 0, 400000, stream);   // zero deg + cnt2

    gemm_kernel<<<(NROWS + 63) / 64, 256, 0, stream>>>(h, Wfc, Wat, Wh16, ssrc, sdst);
    degree_kernel<<<EE / 256, 256, 0, stream>>>(ei, deg);
    scan1_kernel<<<NB, 1024, 0, stream>>>(deg, offs, bsum);
    scan2_kernel<<<1, 64, 0, stream>>>(bsum, bscan, offs);
    scan3_kernel<<<NB, 1024, 0, stream>>>(offs, bscan);
    scatter_kernel<<<EE / 256, 256, 0, stream>>>(ei, offs, cnt2, ssrc, sdst, slist, elist);
    aggregate_kernel<<<NN / 4, 256, 0, stream>>>((const unsigned int*)Wh16, offs, slist, elist, out);
}

// Round 7
// 184.810 us; speedup vs baseline: 1.8557x; 1.0320x over previous
//
#include <hip/hip_runtime.h>
#include <math.h>

#define NN 50000
#define EE 800000
#define DDIM 128
#define NROWS 100000   // B*N
#define NB 49          // ceil(NN/1024) scan blocks

typedef __attribute__((ext_vector_type(8))) short bf16x8;
typedef __attribute__((ext_vector_type(4))) float f32x4;

__device__ __forceinline__ float lrelu(float x) { return x > 0.f ? x : 0.2f * x; }
__device__ __forceinline__ float eluf(float x)  { return x > 0.f ? x : expm1f(x); }

__device__ __forceinline__ unsigned short f2bf(float f) {
    unsigned int u = __float_as_uint(f);
    u += 0x7fffu + ((u >> 16) & 1u);          // RNE
    return (unsigned short)(u >> 16);
}
__device__ __forceinline__ float bflo(unsigned int v) { return __uint_as_float(v << 16); }
__device__ __forceinline__ float bfhi(unsigned int v) { return __uint_as_float(v & 0xffff0000u); }

// ---------------------------------------------------------------------------
// MFMA GEMM: Wh16[row][o] = bf16( sum_k h[row][k] * Wfc[o][k] )
// + fused scores written as [node][batch] float pairs.
// ---------------------------------------------------------------------------
__global__ __launch_bounds__(256) void gemm_kernel(const float* __restrict__ h,
                                                   const float* __restrict__ Wfc,
                                                   const float* __restrict__ Wat,
                                                   unsigned short* __restrict__ Wh16,
                                                   float* __restrict__ ssrc2,
                                                   float* __restrict__ sdst2) {
    __shared__ uint4 Wlds4[2048];              // 32 KB: 128 cols x 256 B
    char* WldsB = (char*)Wlds4;
    const int tid = threadIdx.x;

    // ---- stage W -> LDS bf16, swizzled ----
    {
        const int colw = tid & 127;
        const int kh   = tid >> 7;             // 0..1
#pragma unroll
        for (int q = 0; q < 8; ++q) {
            int k0 = kh * 64 + q * 8;
            float4 w0 = *(const float4*)&Wfc[colw * DDIM + k0];
            float4 w1 = *(const float4*)&Wfc[colw * DDIM + k0 + 4];
            union { uint4 q4; unsigned short u[8]; } pk;
            pk.u[0] = f2bf(w0.x); pk.u[1] = f2bf(w0.y);
            pk.u[2] = f2bf(w0.z); pk.u[3] = f2bf(w0.w);
            pk.u[4] = f2bf(w1.x); pk.u[5] = f2bf(w1.y);
            pk.u[6] = f2bf(w1.z); pk.u[7] = f2bf(w1.w);
            int ba = colw * 256 + k0 * 2;
            ba ^= (colw & 15) << 4;
            *(uint4*)(WldsB + ba) = pk.q4;
        }
    }
    __syncthreads();

    const int lane = tid & 63;
    const int wv   = tid >> 6;
    const long mbase = (long)blockIdx.x * 64 + wv * 16;
    if (mbase >= NROWS) return;                // tail block: extra waves idle

    const int c  = lane & 15;                  // A row / D col within tile
    const int kg = lane >> 4;                  // k-group 0..3

    // ---- A fragments: global fp32 -> bf16 regs ----
    union Af { bf16x8 v; unsigned short u[8]; };
    Af af[4];
    const float* arow = h + (mbase + c) * DDIM + kg * 8;
#pragma unroll
    for (int kk = 0; kk < 4; ++kk) {
        float4 x = *(const float4*)(arow + kk * 32);
        float4 y = *(const float4*)(arow + kk * 32 + 4);
        af[kk].u[0] = f2bf(x.x); af[kk].u[1] = f2bf(x.y);
        af[kk].u[2] = f2bf(x.z); af[kk].u[3] = f2bf(x.w);
        af[kk].u[4] = f2bf(y.x); af[kk].u[5] = f2bf(y.y);
        af[kk].u[6] = f2bf(y.z); af[kk].u[7] = f2bf(y.w);
    }

    // ---- MFMA main: 8 col-tiles x 4 k-steps ----
    f32x4 acc[8];
#pragma unroll
    for (int t = 0; t < 8; ++t) acc[t] = (f32x4){0.f, 0.f, 0.f, 0.f};
#pragma unroll
    for (int t = 0; t < 8; ++t) {
        int colbase = (t * 16 + c) * 256;
        int sw = c << 4;
#pragma unroll
        for (int kk = 0; kk < 4; ++kk) {
            int ba = (colbase + kk * 64 + kg * 16) ^ sw;
            bf16x8 b = *(const bf16x8*)(WldsB + ba);
            acc[t] = __builtin_amdgcn_mfma_f32_16x16x32_bf16(af[kk].v, b, acc[t], 0, 0, 0);
        }
    }

    // ---- store Wh16 (D: col = t*16+c, row = mbase + kg*4 + r) ----
#pragma unroll
    for (int t = 0; t < 8; ++t) {
#pragma unroll
        for (int r = 0; r < 4; ++r) {
            Wh16[(mbase + kg * 4 + r) * DDIM + t * 16 + c] = f2bf(acc[t][r]);
        }
    }

    // ---- fused scores ----
    float asv[8], adv[8];
#pragma unroll
    for (int t = 0; t < 8; ++t) {
        asv[t] = Wat[t * 16 + c];
        adv[t] = Wat[DDIM + t * 16 + c];
    }
#pragma unroll
    for (int r = 0; r < 4; ++r) {
        float ps = 0.f, pd = 0.f;
#pragma unroll
        for (int t = 0; t < 8; ++t) {
            ps += acc[t][r] * asv[t];
            pd += acc[t][r] * adv[t];
        }
#pragma unroll
        for (int o = 1; o <= 8; o <<= 1) {
            ps += __shfl_xor(ps, o);
            pd += __shfl_xor(pd, o);
        }
        if (c == 0) {
            long row = mbase + kg * 4 + r;       // row = b*NN + n
            int b = row >= NN;
            long n = row - (long)b * NN;
            ssrc2[2 * n + b] = ps;
            sdst2[2 * n + b] = pd;
        }
    }
}

// ---------------------------------------------------------------------------
// CSR build: degree -> 3-kernel parallel exclusive scan -> scatter
// ---------------------------------------------------------------------------
__global__ __launch_bounds__(256) void degree_kernel(const int* __restrict__ ei,
                                                     int* __restrict__ deg) {
    int e = blockIdx.x * 256 + threadIdx.x;
    if (e < EE) atomicAdd(&deg[ei[EE + e]], 1);
}

__global__ __launch_bounds__(1024) void scan1_kernel(const int* __restrict__ deg,
                                                     int* __restrict__ offs,
                                                     int* __restrict__ bsum) {
    __shared__ int wsum[16];
    const int tid = threadIdx.x, lane = tid & 63, wid = tid >> 6;
    const int i = blockIdx.x * 1024 + tid;
    int v = (i < NN) ? deg[i] : 0;
    int x = v;
#pragma unroll
    for (int o = 1; o < 64; o <<= 1) {
        int t = __shfl_up(x, o);
        if (lane >= o) x += t;
    }
    if (lane == 63) wsum[wid] = x;
    __syncthreads();
    if (wid == 0) {
        int s = (lane < 16) ? wsum[lane] : 0;
#pragma unroll
        for (int o = 1; o < 16; o <<= 1) {
            int t = __shfl_up(s, o);
            if (lane >= o) s += t;
        }
        if (lane < 16) wsum[lane] = s;
    }
    __syncthreads();
    int waveoff = (wid > 0) ? wsum[wid - 1] : 0;
    if (i < NN) offs[i] = x - v + waveoff;          // block-local exclusive
    if (tid == 0) bsum[blockIdx.x] = wsum[15];      // block total
}

__global__ __launch_bounds__(64) void scan2_kernel(const int* __restrict__ bsum,
                                                   int* __restrict__ bscan,
                                                   int* __restrict__ offs) {
    const int lane = threadIdx.x;
    int v = (lane < NB) ? bsum[lane] : 0;
    int x = v;
#pragma unroll
    for (int o = 1; o < 64; o <<= 1) {
        int t = __shfl_up(x, o);
        if (lane >= o) x += t;
    }
    if (lane < NB) bscan[lane] = x - v;
    if (lane == 63) offs[NN] = x;                   // total = EE
}

__global__ __launch_bounds__(1024) void scan3_kernel(int* __restrict__ offs,
                                                     const int* __restrict__ bscan) {
    const int i = blockIdx.x * 1024 + threadIdx.x;
    if (i < NN) offs[i] += bscan[blockIdx.x];
}

// scatter: one 16B record per edge {src, w0bits, w1bits, 0}
__global__ __launch_bounds__(256) void scatter_kernel(const int* __restrict__ ei,
                                                      const int* __restrict__ offs,
                                                      int* __restrict__ cnt2,
                                                      const float* __restrict__ ssrc2,
                                                      const float* __restrict__ sdst2,
                                                      uint4* __restrict__ elist) {
    int e = blockIdx.x * 256 + threadIdx.x;
    if (e < EE) {
        int dst = ei[EE + e];
        int src = ei[e];
        int p = offs[dst] + atomicAdd(&cnt2[dst], 1);
        float2 ss = ((const float2*)ssrc2)[src];
        float2 sd = ((const float2*)sdst2)[dst];
        float e0 = __expf(lrelu(ss.x + sd.x));
        float e1 = __expf(lrelu(ss.y + sd.y));
        elist[p] = make_uint4((unsigned)src, __float_as_uint(e0), __float_as_uint(e1), 0u);
    }
}

// ---------------------------------------------------------------------------
// aggregate: one wave per (dst, batch); 4-way edge split (16 lanes/edge,
// each lane loads uint4 = 8 bf16 features -> 16 lanes cover the 256B row).
// ---------------------------------------------------------------------------
__global__ __launch_bounds__(256) void aggregate_kernel(const unsigned int* __restrict__ Wh16u,
                                                        const int* __restrict__ offs,
                                                        const uint4* __restrict__ elist,
                                                        float* __restrict__ out) {
    const int lane = threadIdx.x & 63;
    const int wid  = threadIdx.x >> 6;
    const int d    = blockIdx.x * 2 + (wid >> 1);
    const int b    = wid & 1;

    const int grp = lane >> 4;     // 0..3: which edge of the quad
    const int fl  = lane & 15;     // feature slice (8 feats)

    float* o = out + ((long)b * NN + d) * DDIM;

    const int base   = offs[d];
    const int degree = offs[d + 1] - base;
    if (degree == 0) {
        if (lane < 16) {
            float4 z = {0.f, 0.f, 0.f, 0.f};
            ((float4*)o)[2 * fl]     = z;
            ((float4*)o)[2 * fl + 1] = z;
        }
        return;
    }

    const uint4* rec = elist + base;
    const unsigned int* WB = Wh16u + (long)b * NN * 64;

    f32x4 accA = {0,0,0,0}, accB = {0,0,0,0};
    float ds = 0.f;

    for (int ch = 0; ch < degree; ch += 64) {
        int i = ch + lane;
        int s = 0; float w = 0.f;
        if (i < degree) {
            uint4 r = rec[i];
            s = (int)r.x;
            w = __uint_as_float(b ? r.z : r.y);
            ds += w;
        }
        int cnt   = min(64, degree - ch);
        int quads = (cnt + 3) >> 2;
        for (int j = 0; j < quads; ++j) {
            int idx = 4 * j + grp;               // lanes past cnt carry w=0
            int   sj = __shfl(s, idx);
            float wj = __shfl(w, idx);
            uint4 v = ((const uint4*)(WB + (long)sj * 64))[fl];
            accA.x += wj * bflo(v.x); accA.y += wj * bfhi(v.x);
            accA.z += wj * bflo(v.y); accA.w += wj * bfhi(v.y);
            accB.x += wj * bflo(v.z); accB.y += wj * bfhi(v.z);
            accB.z += wj * bflo(v.w); accB.w += wj * bfhi(v.w);
        }
    }

    // merge the 4 edge-groups (same feature slice at lanes l, l^16, l^32, l^48)
#pragma unroll
    for (int m = 32; m >= 16; m >>= 1) {
        accA.x += __shfl_xor(accA.x, m); accA.y += __shfl_xor(accA.y, m);
        accA.z += __shfl_xor(accA.z, m); accA.w += __shfl_xor(accA.w, m);
        accB.x += __shfl_xor(accB.x, m); accB.y += __shfl_xor(accB.y, m);
        accB.z += __shfl_xor(accB.z, m); accB.w += __shfl_xor(accB.w, m);
    }
#pragma unroll
    for (int m = 32; m > 0; m >>= 1) ds += __shfl_xor(ds, m);
    const float inv = 1.f / ds;

    if (lane < 16) {
        float4 rA = { eluf(accA.x * inv), eluf(accA.y * inv),
                      eluf(accA.z * inv), eluf(accA.w * inv) };
        float4 rB = { eluf(accB.x * inv), eluf(accB.y * inv),
                      eluf(accB.z * inv), eluf(accB.w * inv) };
        ((float4*)o)[2 * fl]     = rA;
        ((float4*)o)[2 * fl + 1] = rB;
    }
}

// ---------------------------------------------------------------------------
extern "C" void kernel_launch(void* const* d_in, const int* in_sizes, int n_in,
                              void* d_out, int out_size, void* d_ws, size_t ws_size,
                              hipStream_t stream) {
    (void)in_sizes; (void)n_in; (void)out_size; (void)ws_size;
    const float* h   = (const float*)d_in[0];
    const int*   ei  = (const int*)d_in[1];
    const float* Wfc = (const float*)d_in[2];
    const float* Wat = (const float*)d_in[3];
    float* out = (float*)d_out;

    char* ws = (char*)d_ws;
    unsigned short* Wh16 = (unsigned short*)(ws + 0);   // 25,600,000 B
    float*  ssrc2 = (float*)(ws + 25600000);            //    400,000 B  [node][batch]
    float*  sdst2 = (float*)(ws + 26000000);            //    400,000 B
    uint4*  elist = (uint4*)(ws + 26400000);            // 12,800,000 B
    int*    offs  = (int*)  (ws + 39200000);            //    200,448 B
    int*    deg   = (int*)  (ws + 39400448);            //    200,000 B
    int*    cnt2  = (int*)  (ws + 39600448);            //    200,000 B (contiguous w/ deg)
    int*    bsum  = (int*)  (ws + 39800448);            //        256 B
    int*    bscan = (int*)  (ws + 39800704);            //        256 B

    hipMemsetAsync(deg, 0, 400000, stream);   // zero deg + cnt2

    gemm_kernel<<<(NROWS + 63) / 64, 256, 0, stream>>>(h, Wfc, Wat, Wh16, ssrc2, sdst2);
    degree_kernel<<<EE / 256, 256, 0, stream>>>(ei, deg);
    scan1_kernel<<<NB, 1024, 0, stream>>>(deg, offs, bsum);
    scan2_kernel<<<1, 64, 0, stream>>>(bsum, bscan, offs);
    scan3_kernel<<<NB, 1024, 0, stream>>>(offs, bscan);
    scatter_kernel<<<EE / 256, 256, 0, stream>>>(ei, offs, cnt2, ssrc2, sdst2, elist);
    aggregate_kernel<<<NN / 2, 256, 0, stream>>>((const unsigned int*)Wh16, offs, elist, out);
}